// Round 12
// baseline (69.231 us; speedup 1.0000x reference)
//
#include <hip/hip_runtime.h>
#include <math.h>

#define BATCH 256
#define FEAT 128
#define CAP 100000
#define ROWF 168
#define K 5
#define NBLK2 782           // gemm blocks of 128 keys; 782*128 = 100096
#define NTILE 6256          // 16-key tiles (NBLK2*8)
#define NCHK 6256           // tmax stride
#define NCHKR 6250          // real (non-pad) chunks: CAP/16 exactly
#define SCPT 7              // ceil(NCHKR/1024)
#define MAXSEL 48
#define MARGIN 0.008f

// out layout (floats): retrieved [0,215040) | top_sims | valid_mask | top_idx
#define OUT_SIMS 215040
#define OUT_MASK 216320
#define OUT_IDX  217600

// ws layout (float units)
#define WS_QF    0                 // 4096 uint4 = 16384 floats (bf16 B-frags)
#define WS_KF    16384             // NTILE*4*64 uint4 = 6406144 floats (bf16 A-frags, scaled)
#define WS_TMAX  6422528           // 256*6256 f32 chunk maxima
// total 8,024,064 floats = 32.1 MB (ws is ~268 MB per fill evidence)

typedef __attribute__((ext_vector_type(8))) short short8;
typedef __attribute__((ext_vector_type(4))) float f32x4;

#define BET(vs,vi,ss,ii) ((vs) > (ss) || ((vs) == (ss) && (vi) < (ii)))

__device__ __forceinline__ unsigned short f2bf(float f) {
  unsigned u = __float_as_uint(f);
  u += 0x7fffu + ((u >> 16) & 1u);     // RNE (proven R4-R11)
  return (unsigned short)(u >> 16);
}
__device__ __forceinline__ unsigned pack2(float a, float b) {
  return (unsigned)f2bf(a) | ((unsigned)f2bf(b) << 16);
}

// sorted-5 insert, explicit (value desc, idx asc) tie-break
__device__ __forceinline__ void ins_cmp(float v, int k, float (&s)[5], int (&i)[5]) {
  if (BET(v,k,s[4],i[4])) {
    if (BET(v,k,s[3],i[3])) { s[4]=s[3]; i[4]=i[3];
      if (BET(v,k,s[2],i[2])) { s[3]=s[2]; i[3]=i[2];
        if (BET(v,k,s[1],i[1])) { s[2]=s[1]; i[2]=i[1];
          if (BET(v,k,s[0],i[0])) { s[1]=s[0]; i[1]=i[0]; s[0]=v; i[0]=k; }
          else { s[1]=v; i[1]=k; } }
        else { s[2]=v; i[2]=k; } }
      else { s[3]=v; i[3]=k; } }
    else { s[4]=v; i[4]=k; }
  }
}

// grid 16+NTILE, block 256 (16 rows x 16 dim-slices).
// blocks 0..15 : bf16 B-fragments for 16 queries each (qF).
// blocks 16..  : scaled bf16 A-fragments for one 16-key tile (kF), scale
//                decay/||k|| baked in (R5 prep_k scheme, proven); pad keys -> 0.
__global__ __launch_bounds__(256) void prep2(
    const float* __restrict__ query, const float* __restrict__ keys,
    const int* __restrict__ ts, const int* __restrict__ gstep,
    uint4* __restrict__ qF, uint4* __restrict__ kF) {
  int b = blockIdx.x, tid = threadIdx.x;
  int rid = tid >> 4, dp = tid & 15;
  if (b < 16) {
    int q_ = b*16 + rid;
    const float4* src = reinterpret_cast<const float4*>(query + (size_t)q_*FEAT + dp*8);
    float4 v0 = src[0], v1 = src[1];
    float ss = v0.x*v0.x + v0.y*v0.y + v0.z*v0.z + v0.w*v0.w
             + v1.x*v1.x + v1.y*v1.y + v1.z*v1.z + v1.w*v1.w;
    ss += __shfl_xor(ss,1); ss += __shfl_xor(ss,2);
    ss += __shfl_xor(ss,4); ss += __shfl_xor(ss,8);
    float inv = 1.0f / fmaxf(sqrtf(ss), 1e-12f);
    v0.x*=inv; v0.y*=inv; v0.z*=inv; v0.w*=inv;
    v1.x*=inv; v1.y*=inv; v1.z*=inv; v1.w*=inv;
    uint4 pk;
    pk.x = pack2(v0.x,v0.y); pk.y = pack2(v0.z,v0.w);
    pk.z = pack2(v1.x,v1.y); pk.w = pack2(v1.z,v1.w);
    int s_ = dp >> 2, lg = dp & 3;
    qF[(b*4 + s_)*64 + lg*16 + rid] = pk;
  } else {
    int tile = b - 16;
    int key = tile*16 + rid;
    int gk = key < CAP ? key : CAP-1;
    const float4* kp = reinterpret_cast<const float4*>(keys + (size_t)gk*FEAT + dp*8);
    float4 v0 = kp[0], v1 = kp[1];
    float ss = v0.x*v0.x + v0.y*v0.y + v0.z*v0.z + v0.w*v0.w
             + v1.x*v1.x + v1.y*v1.y + v1.z*v1.z + v1.w*v1.w;
    ss += __shfl_xor(ss,1); ss += __shfl_xor(ss,2);
    ss += __shfl_xor(ss,4); ss += __shfl_xor(ss,8);
    float scl = 0.0f;
    if (key < CAP) {
      float age = (float)(gstep[0] - ts[key]);
      scl = exp2f(age * -0.00723157f) / fmaxf(sqrtf(ss), 1e-12f);  // approx path only
    }
    uint4 pk;
    pk.x = pack2(v0.x*scl, v0.y*scl); pk.y = pack2(v0.z*scl, v0.w*scl);
    pk.z = pack2(v1.x*scl, v1.y*scl); pk.w = pack2(v1.z*scl, v1.w*scl);
    __shared__ uint4 tr[4][64];
    int s_ = dp >> 2, lg = dp & 3;
    tr[s_][lg*16 + rid] = pk;
    __syncthreads();
    int s = tid >> 6, l = tid & 63;
    kF[((size_t)tile*4 + s)*64 + l] = tr[s][l];   // 256 lanes x 16B coalesced
  }
}

// grid NBLK2 (128 keys/block), block 512 (8 waves; wave w owns q-groups 2w,2w+1).
// Staging via global_load_lds DMA (4 x 1KB per wave, zero staging VALU/VGPR),
// then MFMA from LDS, per-16-key-tile maxima (scale already baked into kF).
__global__ __launch_bounds__(512, 4) void gemm_max4(
    const uint4* __restrict__ kF, const uint4* __restrict__ qF,
    float* __restrict__ tmax) {
  __shared__ uint4 lds_kf[32*64];      // 32 KB: 8 tiles x 4 slabs x 64 lanes
  int tid = threadIdx.x;
  int w = tid >> 6, lane = tid & 63;
  int blk = blockIdx.x;

  // issue DMA staging: wave w copies slabs 4w..4w+3 (each 64 lanes x 16B)
  #pragma unroll
  for (int i = 0; i < 4; ++i) {
    int sg = w*4 + i;
    const uint4* g = kF + ((size_t)blk*32 + sg)*64 + lane;
    __builtin_amdgcn_global_load_lds(
        (const __attribute__((address_space(1))) void*)g,
        (__attribute__((address_space(3))) void*)&lds_kf[sg*64], 16, 0, 0);
  }

  short8 qf0[4], qf1[4];
  #pragma unroll
  for (int s_ = 0; s_ < 4; ++s_) {
    qf0[s_] = __builtin_bit_cast(short8, qF[((2*w  )*4 + s_)*64 + lane]);
    qf1[s_] = __builtin_bit_cast(short8, qF[((2*w+1)*4 + s_)*64 + lane]);
  }
  __syncthreads();   // drains vmcnt (DMA) before LDS reads

  float tm0[8], tm1[8];
  #pragma unroll
  for (int t = 0; t < 8; ++t) {
    f32x4 acc0 = {0.f,0.f,0.f,0.f}, acc1 = {0.f,0.f,0.f,0.f};
    #pragma unroll
    for (int s_ = 0; s_ < 4; ++s_) {
      short8 a = __builtin_bit_cast(short8, lds_kf[(t*4 + s_)*64 + lane]);
      acc0 = __builtin_amdgcn_mfma_f32_16x16x32_bf16(a, qf0[s_], acc0, 0,0,0);
      acc1 = __builtin_amdgcn_mfma_f32_16x16x32_bf16(a, qf1[s_], acc1, 0,0,0);
    }
    // C/D: col=lane&15 (query), row=(lane>>4)*4+r (key). Pad keys are zero
    // fragments -> sims 0; select scans only the 6250 real chunks.
    float m0 = fmaxf(fmaxf(acc0[0],acc0[1]), fmaxf(acc0[2],acc0[3]));
    float m1 = fmaxf(fmaxf(acc1[0],acc1[1]), fmaxf(acc1[2],acc1[3]));
    m0 = fmaxf(m0, __shfl_xor(m0,16)); m0 = fmaxf(m0, __shfl_xor(m0,32));
    m1 = fmaxf(m1, __shfl_xor(m1,16)); m1 = fmaxf(m1, __shfl_xor(m1,32));
    tm0[t] = m0; tm1[t] = m1;
  }

  if (lane < 16) {
    int q0 = w*32 + lane, q1 = q0 + 16;
    float4 a0 = {tm0[0],tm0[1],tm0[2],tm0[3]};
    float4 a1 = {tm0[4],tm0[5],tm0[6],tm0[7]};
    float4 b0 = {tm1[0],tm1[1],tm1[2],tm1[3]};
    float4 b1 = {tm1[4],tm1[5],tm1[6],tm1[7]};
    float4* p0 = reinterpret_cast<float4*>(&tmax[(size_t)q0*NCHK + blk*8]);
    float4* p1 = reinterpret_cast<float4*>(&tmax[(size_t)q1*NCHK + blk*8]);
    p0[0] = a0; p0[1] = a1;
    p1[0] = b0; p1[1] = b1;
  }
}

// grid 256 (1/query), block 1024 (16 waves). Loads hoisted before insert
// chains; scans only the 6250 real chunks; m5a -> margin select -> exact f32
// rescore -> exact top-5 + gather.
__global__ __launch_bounds__(1024) void select_rescore3(
    const float* __restrict__ tmax, const float* __restrict__ keys,
    const float* __restrict__ query, const int* __restrict__ ts,
    const int* __restrict__ gstep, const float* __restrict__ values,
    float* __restrict__ out) {
  int q = blockIdx.x, tid = threadIdx.x;
  int w = tid >> 6, lane = tid & 63;
  int gstep0 = gstep[0];

  // normalize own query row (prep's exact op order -> bit-identical qn)
  __shared__ float qrow[FEAT];
  if (tid < 16) {
    int d0 = tid * 8;
    const float4* src = reinterpret_cast<const float4*>(query + (size_t)q*FEAT + d0);
    float4 v0 = src[0], v1 = src[1];
    float ss = v0.x*v0.x + v0.y*v0.y + v0.z*v0.z + v0.w*v0.w
             + v1.x*v1.x + v1.y*v1.y + v1.z*v1.z + v1.w*v1.w;
    ss += __shfl_xor(ss,1); ss += __shfl_xor(ss,2);
    ss += __shfl_xor(ss,4); ss += __shfl_xor(ss,8);
    float inv = 1.0f / fmaxf(sqrtf(ss), 1e-12f);
    v0.x*=inv; v0.y*=inv; v0.z*=inv; v0.w*=inv;
    v1.x*=inv; v1.y*=inv; v1.z*=inv; v1.w*=inv;
    float4* dst = reinterpret_cast<float4*>(qrow + d0);
    dst[0] = v0; dst[1] = v1;
  }
  __syncthreads();

  // phase 1: load all chunk maxima first (independent loads in flight),
  // then insert-chain
  float cs[SCPT];
  #pragma unroll
  for (int j = 0; j < SCPT; ++j) {
    int c = tid + j*1024;
    cs[j] = (c < NCHKR) ? tmax[(size_t)q*NCHK + c] : -INFINITY;
  }
  float s5[5] = {-INFINITY,-INFINITY,-INFINITY,-INFINITY,-INFINITY};
  int   i5[5] = {0x7fffffff,0x7fffffff,0x7fffffff,0x7fffffff,0x7fffffff};
  #pragma unroll
  for (int j = 0; j < SCPT; ++j) {
    int c = tid + j*1024;
    ins_cmp(cs[j], (c < NCHKR) ? c : 0x7fffffff, s5, i5);
  }
  #pragma unroll
  for (int off = 1; off < 64; off <<= 1) {
    float ps[5]; int pi[5];
    #pragma unroll
    for (int j=0;j<5;++j){ ps[j]=__shfl_xor(s5[j],off); pi[j]=__shfl_xor(i5[j],off); }
    #pragma unroll
    for (int j=0;j<5;++j) ins_cmp(ps[j], pi[j], s5, i5);
  }
  __shared__ float rS[16][5]; __shared__ int rI[16][5];
  if (lane == 0) {
    #pragma unroll
    for (int j=0;j<5;++j){ rS[w][j]=s5[j]; rI[w][j]=i5[j]; }
  }
  __syncthreads();
  __shared__ float thSh;
  if (tid == 0) {
    float fs[5]; int fi[5];
    #pragma unroll
    for (int j=0;j<5;++j){ fs[j]=rS[0][j]; fi[j]=rI[0][j]; }
    for (int ww = 1; ww < 16; ++ww)
      #pragma unroll
      for (int j=0;j<5;++j) ins_cmp(rS[ww][j], rI[ww][j], fs, fi);
    thSh = fs[4] - MARGIN;     // m5a - margin
  }
  __syncthreads();
  float th = thSh;

  // phase 2: select chunks within margin
  __shared__ int cnt; __shared__ int clist[MAXSEL];
  if (tid == 0) cnt = 0;
  __syncthreads();
  #pragma unroll
  for (int j = 0; j < SCPT; ++j) {
    int c = tid + j*1024;
    if (c < NCHKR && cs[j] >= th) {
      int p = atomicAdd(&cnt, 1);
      if (p < MAXSEL) clist[p] = c;
    }
  }
  __syncthreads();
  int nsel = cnt < MAXSEL ? cnt : MAXSEL;

  // phase 3: exact f32 rescore, 4 threads/key (wave = 16 consecutive keys)
  __shared__ float exs[MAXSEL*16];
  for (int s4 = tid; s4 < nsel*64; s4 += 1024) {
    int slot = s4 >> 2, part = s4 & 3;
    int key = clist[slot >> 4]*16 + (slot & 15);
    float dot = 0.f, ksq = 0.f;
    if (key < CAP) {
      const float4* kp = reinterpret_cast<const float4*>(keys + (size_t)key*FEAT + part*32);
      const float4* qp = reinterpret_cast<float4*>(qrow) + part*8;
      #pragma unroll
      for (int d = 0; d < 8; ++d) {
        float4 kv = kp[d];
        float4 qv = qp[d];
        dot = fmaf(kv.w,qv.w,fmaf(kv.z,qv.z,fmaf(kv.y,qv.y,fmaf(kv.x,qv.x,dot))));
        ksq = fmaf(kv.w,kv.w,fmaf(kv.z,kv.z,fmaf(kv.y,kv.y,fmaf(kv.x,kv.x,ksq))));
      }
    }
    dot += __shfl_xor(dot,1); dot += __shfl_xor(dot,2);
    ksq += __shfl_xor(ksq,1); ksq += __shfl_xor(ksq,2);
    if (part == 0) {
      float sim = -INFINITY;
      if (key < CAP) {
        float age = (float)(gstep0 - ts[key]);
        sim = dot / fmaxf(sqrtf(ksq), 1e-12f) * powf(0.995f, age);
      }
      exs[slot] = sim;
    }
  }
  __syncthreads();

  // phase 4: single-pass exact top-5 (nsel*16 <= 768 <= 1024 threads)
  float fs5[5] = {-INFINITY,-INFINITY,-INFINITY,-INFINITY,-INFINITY};
  int   fi5[5] = {0x7fffffff,0x7fffffff,0x7fffffff,0x7fffffff,0x7fffffff};
  if (tid < nsel*16) {
    fs5[0] = exs[tid];
    fi5[0] = clist[tid >> 4]*16 + (tid & 15);
  }
  #pragma unroll
  for (int off = 1; off < 64; off <<= 1) {
    float ps[5]; int pi[5];
    #pragma unroll
    for (int j=0;j<5;++j){ ps[j]=__shfl_xor(fs5[j],off); pi[j]=__shfl_xor(fi5[j],off); }
    #pragma unroll
    for (int j=0;j<5;++j) ins_cmp(ps[j], pi[j], fs5, fi5);
  }
  if (lane == 0) {
    #pragma unroll
    for (int j=0;j<5;++j){ rS[w][j]=fs5[j]; rI[w][j]=fi5[j]; }
  }
  __syncthreads();
  __shared__ int wix[K];
  if (tid == 0) {
    float fs[5]; int fi[5];
    #pragma unroll
    for (int j=0;j<5;++j){ fs[j]=rS[0][j]; fi[j]=rI[0][j]; }
    for (int ww = 1; ww < 16; ++ww)
      #pragma unroll
      for (int j=0;j<5;++j) ins_cmp(rS[ww][j], rI[ww][j], fs, fi);
    #pragma unroll
    for (int r = 0; r < K; ++r) {
      out[OUT_SIMS + q*K + r] = fs[r];
      out[OUT_MASK + q*K + r] = (fs[r] >= 0.0f) ? 1.0f : 0.0f;
      out[OUT_IDX  + q*K + r] = (float)fi[r];
      wix[r] = fi[r];
    }
  }
  __syncthreads();
  for (int idx = tid; idx < K*ROWF; idx += 1024) {
    int r = idx / ROWF, e = idx - r*ROWF;
    out[(q*K + r)*ROWF + e] = values[(size_t)wix[r]*ROWF + e];
  }
}

extern "C" void kernel_launch(void* const* d_in, const int* in_sizes, int n_in,
                              void* d_out, int out_size, void* d_ws, size_t ws_size,
                              hipStream_t stream) {
  const float* query  = (const float*)d_in[0];
  const float* keys   = (const float*)d_in[1];
  const float* values = (const float*)d_in[2];
  const int*   ts     = (const int*)d_in[3];
  const int*   gstep  = (const int*)d_in[4];

  float* out  = (float*)d_out;
  float* wsf  = (float*)d_ws;
  uint4* qF   = (uint4*)(wsf + WS_QF);
  uint4* kF   = (uint4*)(wsf + WS_KF);
  float* tmax = wsf + WS_TMAX;

  prep2<<<16 + NTILE, 256, 0, stream>>>(query, keys, ts, gstep, qF, kF);
  gemm_max4<<<NBLK2, 512, 0, stream>>>(kF, qF, tmax);
  select_rescore3<<<BATCH, 1024, 0, stream>>>(tmax, keys, query, ts, gstep, values, out);
}

// Round 13
// 49.723 us; speedup vs baseline: 1.3923x; 1.3923x over previous
//
#include <hip/hip_runtime.h>
#include <math.h>

#define BATCH 256
#define FEAT 128
#define CAP 100000
#define ROWF 168
#define K 5
#define NBLKG 1564          // gemm blocks of 64 keys; 1564*64 = 100096
#define NKBP 1564           // prep key-blocks (64 keys each)
#define NCHK 6256           // tmax stride (16-key chunks incl. pad)
#define NCHKR 6250          // real chunks: CAP/16
#define SCPT 7              // ceil(NCHKR/1024)
#define MAXSEL 48
#define MARGIN 0.008f

// out layout (floats): retrieved [0,215040) | top_sims | valid_mask | top_idx
#define OUT_SIMS 215040
#define OUT_MASK 216320
#define OUT_IDX  217600

// ws layout (float units)
#define WS_SCALE 0          // 100096 f32: decay/||k|| (0 for pad keys)
#define WS_QF    100096     // 4096 uint4 = bf16 B-fragments
#define WS_TMAX  116480     // 256*6256 f32 chunk maxima

typedef __attribute__((ext_vector_type(8))) short short8;
typedef __attribute__((ext_vector_type(4))) float f32x4;

#define BET(vs,vi,ss,ii) ((vs) > (ss) || ((vs) == (ss) && (vi) < (ii)))

// round-half-up bf16 pack: 2 VALU/elem; |err| <= 0.5 ulp (same bound as RNE,
// so the MARGIN analysis from R4-R12 is unchanged). a -> low16, b -> high16.
__device__ __forceinline__ unsigned pack2(float a, float b) {
  unsigned ua = (__float_as_uint(a) + 0x8000u) >> 16;
  unsigned ub = (__float_as_uint(b) + 0x8000u) & 0xffff0000u;
  return ua | ub;
}

// value-only sorted-5 insert (desc), branch-skipped, min/max cmp-swap
__device__ __forceinline__ void ins_val(float v, float (&s)[5]) {
  if (v > s[4]) {
    float x = v;
    #pragma unroll
    for (int j = 0; j < 5; ++j) {
      float hi = fmaxf(s[j], x);
      x = fminf(s[j], x);
      s[j] = hi;
    }
  }
}

// (value desc, idx asc) sorted-5 insert for the exact final top-5
__device__ __forceinline__ void ins_cmp(float v, int k, float (&s)[5], int (&i)[5]) {
  if (BET(v,k,s[4],i[4])) {
    if (BET(v,k,s[3],i[3])) { s[4]=s[3]; i[4]=i[3];
      if (BET(v,k,s[2],i[2])) { s[3]=s[2]; i[3]=i[2];
        if (BET(v,k,s[1],i[1])) { s[2]=s[1]; i[2]=i[1];
          if (BET(v,k,s[0],i[0])) { s[1]=s[0]; i[1]=i[0]; s[0]=v; i[0]=k; }
          else { s[1]=v; i[1]=k; } }
        else { s[2]=v; i[2]=k; } }
      else { s[3]=v; i[3]=k; } }
    else { s[4]=v; i[4]=k; }
  }
}

// grid 16+NKBP, block 256 (16 rows x 16 dim-slices).
// blocks 0..15 : bf16 B-fragments for 16 queries each (qF).
// blocks 16..  : scale[key] = 0.995^age / max(||k||,eps) for 64 keys (pad->0).
__global__ __launch_bounds__(256) void prep(
    const float* __restrict__ query, const float* __restrict__ keys,
    const int* __restrict__ ts, const int* __restrict__ gstep,
    uint4* __restrict__ qF, float* __restrict__ scale) {
  int b = blockIdx.x, tid = threadIdx.x;
  int rid = tid >> 4, dp = tid & 15;
  if (b < 16) {
    int q_ = b*16 + rid;
    const float4* src = reinterpret_cast<const float4*>(query + (size_t)q_*FEAT + dp*8);
    float4 v0 = src[0], v1 = src[1];
    float ss = v0.x*v0.x + v0.y*v0.y + v0.z*v0.z + v0.w*v0.w
             + v1.x*v1.x + v1.y*v1.y + v1.z*v1.z + v1.w*v1.w;
    ss += __shfl_xor(ss,1); ss += __shfl_xor(ss,2);
    ss += __shfl_xor(ss,4); ss += __shfl_xor(ss,8);
    float inv = 1.0f / fmaxf(sqrtf(ss), 1e-12f);
    v0.x*=inv; v0.y*=inv; v0.z*=inv; v0.w*=inv;
    v1.x*=inv; v1.y*=inv; v1.z*=inv; v1.w*=inv;
    uint4 pk;
    pk.x = pack2(v0.x,v0.y); pk.y = pack2(v0.z,v0.w);
    pk.z = pack2(v1.x,v1.y); pk.w = pack2(v1.z,v1.w);
    int s_ = dp >> 2, lg = dp & 3;
    qF[(b*4 + s_)*64 + lg*16 + rid] = pk;
  } else {
    int kb = (b - 16) * 64;
    int g0 = gstep[0];
    #pragma unroll
    for (int it = 0; it < 4; ++it) {
      int key = kb + it*16 + rid;
      int gk = key < CAP ? key : CAP-1;
      const float4* kp = reinterpret_cast<const float4*>(keys + (size_t)gk*FEAT + dp*8);
      float4 v0 = kp[0], v1 = kp[1];
      float ss = v0.x*v0.x + v0.y*v0.y + v0.z*v0.z + v0.w*v0.w
               + v1.x*v1.x + v1.y*v1.y + v1.z*v1.z + v1.w*v1.w;
      ss += __shfl_xor(ss,1); ss += __shfl_xor(ss,2);
      ss += __shfl_xor(ss,4); ss += __shfl_xor(ss,8);
      if (dp == 0) {
        float scl = 0.0f;
        if (key < CAP) {
          float age = (float)(g0 - ts[key]);
          scl = exp2f(age * -0.00723157f) / fmaxf(sqrtf(ss), 1e-12f);  // approx only
        }
        scale[key] = scl;
      }
    }
  }
}

// grid NBLKG (64 keys/block), block 512 (8 waves; wave w owns q-groups 2w,2w+1).
// Branchless raw-key bf16 staging (cheap half-up pack) into stride-66 LDS
// slabs, MFMA, scale-table epilogue, per-16-key-tile maxima.
__global__ __launch_bounds__(512, 4) void gemm_max5(
    const float* __restrict__ keys, const float* __restrict__ scale,
    const uint4* __restrict__ qF, float* __restrict__ tmax) {
  __shared__ uint4 lds_kf[16*66];      // 4 tiles x 4 slabs, stride 66 (16.9 KB)
  int tid = threadIdx.x;
  int w = tid >> 6, lane = tid & 63;
  int blk = blockIdx.x;
  int kbase = blk * 64;

  short8 qf0[4], qf1[4];
  #pragma unroll
  for (int s_ = 0; s_ < 4; ++s_) {
    qf0[s_] = __builtin_bit_cast(short8, qF[((2*w  )*4 + s_)*64 + lane]);
    qf1[s_] = __builtin_bit_cast(short8, qF[((2*w+1)*4 + s_)*64 + lane]);
  }

  // stage 64 keys: 2 iters x 32 keys, branchless clamp (pad keys get scale 0)
  int dp = tid & 15;
  #pragma unroll
  for (int it = 0; it < 2; ++it) {
    int kl = it*32 + (tid >> 4);
    int gk = kbase + kl;
    gk = gk < CAP ? gk : CAP-1;
    const float4* kp = reinterpret_cast<const float4*>(keys + (size_t)gk*FEAT + dp*8);
    float4 v0 = kp[0], v1 = kp[1];
    uint4 pk;
    pk.x = pack2(v0.x, v0.y); pk.y = pack2(v0.z, v0.w);
    pk.z = pack2(v1.x, v1.y); pk.w = pack2(v1.z, v1.w);
    int slab = (kl >> 4)*4 + (dp >> 2);
    int slot = (dp & 3)*16 + (kl & 15);
    lds_kf[slab*66 + slot] = pk;
  }
  __syncthreads();

  float tm0[4], tm1[4];
  #pragma unroll
  for (int t = 0; t < 4; ++t) {
    f32x4 acc0 = {0.f,0.f,0.f,0.f}, acc1 = {0.f,0.f,0.f,0.f};
    #pragma unroll
    for (int s_ = 0; s_ < 4; ++s_) {
      short8 a = __builtin_bit_cast(short8, lds_kf[(t*4 + s_)*66 + lane]);
      acc0 = __builtin_amdgcn_mfma_f32_16x16x32_bf16(a, qf0[s_], acc0, 0,0,0);
      acc1 = __builtin_amdgcn_mfma_f32_16x16x32_bf16(a, qf1[s_], acc1, 0,0,0);
    }
    // C/D: col=lane&15 (query), row=(lane>>4)*4+r (key)
    int kb = kbase + t*16 + (lane>>4)*4;
    float4 sc = *reinterpret_cast<const float4*>(&scale[kb]);
    float m0 = fmaxf(fmaxf(acc0[0]*sc.x, acc0[1]*sc.y),
                     fmaxf(acc0[2]*sc.z, acc0[3]*sc.w));
    float m1 = fmaxf(fmaxf(acc1[0]*sc.x, acc1[1]*sc.y),
                     fmaxf(acc1[2]*sc.z, acc1[3]*sc.w));
    m0 = fmaxf(m0, __shfl_xor(m0,16)); m0 = fmaxf(m0, __shfl_xor(m0,32));
    m1 = fmaxf(m1, __shfl_xor(m1,16)); m1 = fmaxf(m1, __shfl_xor(m1,32));
    tm0[t] = m0; tm1[t] = m1;
  }

  if (lane < 16) {
    int q0 = w*32 + lane, q1 = q0 + 16;
    float4 a0 = {tm0[0],tm0[1],tm0[2],tm0[3]};
    float4 b0 = {tm1[0],tm1[1],tm1[2],tm1[3]};
    *reinterpret_cast<float4*>(&tmax[(size_t)q0*NCHK + blk*4]) = a0;
    *reinterpret_cast<float4*>(&tmax[(size_t)q1*NCHK + blk*4]) = b0;
  }
}

// grid 256 (1/query), block 1024 (16 waves). Value-only m5a scan, margin
// select, exact f32 rescore, exact top-5 + gather.
__global__ __launch_bounds__(1024) void select_rescore4(
    const float* __restrict__ tmax, const float* __restrict__ keys,
    const float* __restrict__ query, const int* __restrict__ ts,
    const int* __restrict__ gstep, const float* __restrict__ values,
    float* __restrict__ out) {
  int q = blockIdx.x, tid = threadIdx.x;
  int w = tid >> 6, lane = tid & 63;
  int gstep0 = gstep[0];

  __shared__ float qrow[FEAT];
  if (tid < 16) {
    int d0 = tid * 8;
    const float4* src = reinterpret_cast<const float4*>(query + (size_t)q*FEAT + d0);
    float4 v0 = src[0], v1 = src[1];
    float ss = v0.x*v0.x + v0.y*v0.y + v0.z*v0.z + v0.w*v0.w
             + v1.x*v1.x + v1.y*v1.y + v1.z*v1.z + v1.w*v1.w;
    ss += __shfl_xor(ss,1); ss += __shfl_xor(ss,2);
    ss += __shfl_xor(ss,4); ss += __shfl_xor(ss,8);
    float inv = 1.0f / fmaxf(sqrtf(ss), 1e-12f);
    v0.x*=inv; v0.y*=inv; v0.z*=inv; v0.w*=inv;
    v1.x*=inv; v1.y*=inv; v1.z*=inv; v1.w*=inv;
    float4* dst = reinterpret_cast<float4*>(qrow + d0);
    dst[0] = v0; dst[1] = v1;
  }
  __syncthreads();

  // phase 1: value-only per-thread sorted-5 of chunk maxima
  float cs[SCPT];
  #pragma unroll
  for (int j = 0; j < SCPT; ++j) {
    int c = tid + j*1024;
    cs[j] = (c < NCHKR) ? tmax[(size_t)q*NCHK + c] : -INFINITY;
  }
  float s5[5] = {-INFINITY,-INFINITY,-INFINITY,-INFINITY,-INFINITY};
  #pragma unroll
  for (int j = 0; j < SCPT; ++j) ins_val(cs[j], s5);
  #pragma unroll
  for (int off = 1; off < 64; off <<= 1) {
    float ps[5];
    #pragma unroll
    for (int j=0;j<5;++j) ps[j] = __shfl_xor(s5[j], off);
    #pragma unroll
    for (int j=0;j<5;++j) ins_val(ps[j], s5);
  }
  __shared__ float rS[16][5]; __shared__ int rI[16][5];
  if (lane == 0) {
    #pragma unroll
    for (int j=0;j<5;++j) rS[w][j] = s5[j];
  }
  __syncthreads();
  __shared__ float thSh;
  if (w == 0) {                         // wave-parallel 16-way block merge
    float m5[5] = {-INFINITY,-INFINITY,-INFINITY,-INFINITY,-INFINITY};
    if (lane < 16) {
      #pragma unroll
      for (int j=0;j<5;++j) m5[j] = rS[lane][j];
    }
    #pragma unroll
    for (int off = 1; off < 16; off <<= 1) {
      float ps[5];
      #pragma unroll
      for (int j=0;j<5;++j) ps[j] = __shfl_xor(m5[j], off);
      #pragma unroll
      for (int j=0;j<5;++j) ins_val(ps[j], m5);
    }
    if (lane == 0) thSh = m5[4] - MARGIN;   // m5a - margin
  }
  __syncthreads();
  float th = thSh;

  // phase 2: select chunks within margin (indices recovered here)
  __shared__ int cnt; __shared__ int clist[MAXSEL];
  if (tid == 0) cnt = 0;
  __syncthreads();
  #pragma unroll
  for (int j = 0; j < SCPT; ++j) {
    int c = tid + j*1024;
    if (c < NCHKR && cs[j] >= th) {
      int p = atomicAdd(&cnt, 1);
      if (p < MAXSEL) clist[p] = c;
    }
  }
  __syncthreads();
  int nsel = cnt < MAXSEL ? cnt : MAXSEL;

  // phase 3: exact f32 rescore, 4 threads/key (wave = 16 consecutive keys)
  __shared__ float exs[MAXSEL*16];
  for (int s4 = tid; s4 < nsel*64; s4 += 1024) {
    int slot = s4 >> 2, part = s4 & 3;
    int key = clist[slot >> 4]*16 + (slot & 15);
    float dot = 0.f, ksq = 0.f;
    if (key < CAP) {
      const float4* kp = reinterpret_cast<const float4*>(keys + (size_t)key*FEAT + part*32);
      const float4* qp = reinterpret_cast<float4*>(qrow) + part*8;
      #pragma unroll
      for (int d = 0; d < 8; ++d) {
        float4 kv = kp[d];
        float4 qv = qp[d];
        dot = fmaf(kv.w,qv.w,fmaf(kv.z,qv.z,fmaf(kv.y,qv.y,fmaf(kv.x,qv.x,dot))));
        ksq = fmaf(kv.w,kv.w,fmaf(kv.z,kv.z,fmaf(kv.y,kv.y,fmaf(kv.x,kv.x,ksq))));
      }
    }
    dot += __shfl_xor(dot,1); dot += __shfl_xor(dot,2);
    ksq += __shfl_xor(ksq,1); ksq += __shfl_xor(ksq,2);
    if (part == 0) {
      float sim = -INFINITY;
      if (key < CAP) {
        float age = (float)(gstep0 - ts[key]);
        sim = dot / fmaxf(sqrtf(ksq), 1e-12f) * powf(0.995f, age);
      }
      exs[slot] = sim;
    }
  }
  __syncthreads();

  // phase 4: exact top-5 with idx tie-break (<=768 candidates, 1/thread)
  float fs5[5] = {-INFINITY,-INFINITY,-INFINITY,-INFINITY,-INFINITY};
  int   fi5[5] = {0x7fffffff,0x7fffffff,0x7fffffff,0x7fffffff,0x7fffffff};
  if (tid < nsel*16) {
    fs5[0] = exs[tid];
    fi5[0] = clist[tid >> 4]*16 + (tid & 15);
  }
  #pragma unroll
  for (int off = 1; off < 64; off <<= 1) {
    float ps[5]; int pi[5];
    #pragma unroll
    for (int j=0;j<5;++j){ ps[j]=__shfl_xor(fs5[j],off); pi[j]=__shfl_xor(fi5[j],off); }
    #pragma unroll
    for (int j=0;j<5;++j) ins_cmp(ps[j], pi[j], fs5, fi5);
  }
  if (lane == 0) {
    #pragma unroll
    for (int j=0;j<5;++j){ rS[w][j]=fs5[j]; rI[w][j]=fi5[j]; }
  }
  __syncthreads();
  __shared__ int wix[K];
  if (w == 0) {                         // wave-parallel 16-way final merge
    float fs[5] = {-INFINITY,-INFINITY,-INFINITY,-INFINITY,-INFINITY};
    int   fi[5] = {0x7fffffff,0x7fffffff,0x7fffffff,0x7fffffff,0x7fffffff};
    if (lane < 16) {
      #pragma unroll
      for (int j=0;j<5;++j){ fs[j]=rS[lane][j]; fi[j]=rI[lane][j]; }
    }
    #pragma unroll
    for (int off = 1; off < 16; off <<= 1) {
      float ps[5]; int pi[5];
      #pragma unroll
      for (int j=0;j<5;++j){ ps[j]=__shfl_xor(fs[j],off); pi[j]=__shfl_xor(fi[j],off); }
      #pragma unroll
      for (int j=0;j<5;++j) ins_cmp(ps[j], pi[j], fs, fi);
    }
    if (lane == 0) {
      #pragma unroll
      for (int r = 0; r < K; ++r) {
        out[OUT_SIMS + q*K + r] = fs[r];
        out[OUT_MASK + q*K + r] = (fs[r] >= 0.0f) ? 1.0f : 0.0f;
        out[OUT_IDX  + q*K + r] = (float)fi[r];
        wix[r] = fi[r];
      }
    }
  }
  __syncthreads();
  for (int idx = tid; idx < K*ROWF; idx += 1024) {
    int r = idx / ROWF, e = idx - r*ROWF;
    out[(q*K + r)*ROWF + e] = values[(size_t)wix[r]*ROWF + e];
  }
}

extern "C" void kernel_launch(void* const* d_in, const int* in_sizes, int n_in,
                              void* d_out, int out_size, void* d_ws, size_t ws_size,
                              hipStream_t stream) {
  const float* query  = (const float*)d_in[0];
  const float* keys   = (const float*)d_in[1];
  const float* values = (const float*)d_in[2];
  const int*   ts     = (const int*)d_in[3];
  const int*   gstep  = (const int*)d_in[4];

  float* out   = (float*)d_out;
  float* wsf   = (float*)d_ws;
  float* scale = wsf + WS_SCALE;
  uint4* qF    = (uint4*)(wsf + WS_QF);
  float* tmax  = wsf + WS_TMAX;

  prep<<<16 + NKBP, 256, 0, stream>>>(query, keys, ts, gstep, qF, scale);
  gemm_max5<<<NBLKG, 512, 0, stream>>>(keys, scale, qF, tmax);
  select_rescore4<<<BATCH, 1024, 0, stream>>>(tmax, keys, query, ts, gstep, values, out);
}

// Round 14
// 46.455 us; speedup vs baseline: 1.4903x; 1.0703x over previous
//
#include <hip/hip_runtime.h>
#include <math.h>

#define BATCH 256
#define FEAT 128
#define CAP 100000
#define ROWF 168
#define K 5
#define NBLKG 1564          // gemm blocks of 64 keys; 1564*64 = 100096
#define NCHK 6256           // tmax stride (16-key chunks incl. pad)
#define NCHKR 6250          // real chunks: CAP/16
#define SCPT 7              // ceil(NCHKR/1024)
#define MAXSEL 48
#define MARGIN 0.008f

// out layout (floats): retrieved [0,215040) | top_sims | valid_mask | top_idx
#define OUT_SIMS 215040
#define OUT_MASK 216320
#define OUT_IDX  217600

// ws layout (float units)
#define WS_QF    0          // 4096 uint4 = bf16 B-fragments
#define WS_TMAX  16384      // 256*6256 f32 chunk maxima

typedef __attribute__((ext_vector_type(8))) short short8;
typedef __attribute__((ext_vector_type(4))) float f32x4;

#define BET(vs,vi,ss,ii) ((vs) > (ss) || ((vs) == (ss) && (vi) < (ii)))

// round-half-up bf16 pack: 2 VALU/elem; |err| <= 0.5 ulp (same bound as RNE,
// MARGIN analysis unchanged). a -> low16, b -> high16.
__device__ __forceinline__ unsigned pack2(float a, float b) {
  unsigned ua = (__float_as_uint(a) + 0x8000u) >> 16;
  unsigned ub = (__float_as_uint(b) + 0x8000u) & 0xffff0000u;
  return ua | ub;
}

// value-only sorted-5 insert (desc), branch-skipped, min/max cmp-swap
__device__ __forceinline__ void ins_val(float v, float (&s)[5]) {
  if (v > s[4]) {
    float x = v;
    #pragma unroll
    for (int j = 0; j < 5; ++j) {
      float hi = fmaxf(s[j], x);
      x = fminf(s[j], x);
      s[j] = hi;
    }
  }
}

// (value desc, idx asc) sorted-5 insert for the exact final top-5
__device__ __forceinline__ void ins_cmp(float v, int k, float (&s)[5], int (&i)[5]) {
  if (BET(v,k,s[4],i[4])) {
    if (BET(v,k,s[3],i[3])) { s[4]=s[3]; i[4]=i[3];
      if (BET(v,k,s[2],i[2])) { s[3]=s[2]; i[3]=i[2];
        if (BET(v,k,s[1],i[1])) { s[2]=s[1]; i[2]=i[1];
          if (BET(v,k,s[0],i[0])) { s[1]=s[0]; i[1]=i[0]; s[0]=v; i[0]=k; }
          else { s[1]=v; i[1]=k; } }
        else { s[2]=v; i[2]=k; } }
      else { s[3]=v; i[3]=k; } }
    else { s[4]=v; i[4]=k; }
  }
}

// grid 16, block 256 (16 queries x 16 dim-slices): bf16 B-fragments.
__global__ __launch_bounds__(256) void prep_q(const float* __restrict__ query,
                                              uint4* __restrict__ qF) {
  int b = blockIdx.x, tid = threadIdx.x;
  int rid = tid >> 4, dp = tid & 15;
  int q_ = b*16 + rid;
  const float4* src = reinterpret_cast<const float4*>(query + (size_t)q_*FEAT + dp*8);
  float4 v0 = src[0], v1 = src[1];
  float ss = v0.x*v0.x + v0.y*v0.y + v0.z*v0.z + v0.w*v0.w
           + v1.x*v1.x + v1.y*v1.y + v1.z*v1.z + v1.w*v1.w;
  ss += __shfl_xor(ss,1); ss += __shfl_xor(ss,2);
  ss += __shfl_xor(ss,4); ss += __shfl_xor(ss,8);
  float inv = 1.0f / fmaxf(sqrtf(ss), 1e-12f);
  v0.x*=inv; v0.y*=inv; v0.z*=inv; v0.w*=inv;
  v1.x*=inv; v1.y*=inv; v1.z*=inv; v1.w*=inv;
  uint4 pk;
  pk.x = pack2(v0.x,v0.y); pk.y = pack2(v0.z,v0.w);
  pk.z = pack2(v1.x,v1.y); pk.w = pack2(v1.z,v1.w);
  int s_ = dp >> 2, lg = dp & 3;
  qF[(b*4 + s_)*64 + lg*16 + rid] = pk;
}

// grid NBLKG (64 keys/block), block 512 (8 waves; wave w owns q-groups 2w,2w+1).
// Single pass over keys: staging computes norm+decay scale in-flight
// (ss from already-loaded regs, 16-lane reduce, exp2*rsqrt once per key into
// LDS), packs RAW bf16 keys (scale applied in epilogue -> same numerics as
// R13), MFMA, per-16-key-tile scaled maxima.
__global__ __launch_bounds__(512, 4) void gemm_max6(
    const float* __restrict__ keys, const int* __restrict__ ts,
    const int* __restrict__ gstep, const uint4* __restrict__ qF,
    float* __restrict__ tmax) {
  __shared__ uint4 lds_kf[16*66];      // 4 tiles x 4 slabs, stride 66 (16.9 KB)
  __shared__ float sscale[64];
  int tid = threadIdx.x;
  int w = tid >> 6, lane = tid & 63;
  int blk = blockIdx.x;
  int kbase = blk * 64;
  int g0 = gstep[0];

  short8 qf0[4], qf1[4];
  #pragma unroll
  for (int s_ = 0; s_ < 4; ++s_) {
    qf0[s_] = __builtin_bit_cast(short8, qF[((2*w  )*4 + s_)*64 + lane]);
    qf1[s_] = __builtin_bit_cast(short8, qF[((2*w+1)*4 + s_)*64 + lane]);
  }

  // stage 64 keys: 2 iters x 32 keys; raw bf16 pack + in-flight scale calc
  int dp = tid & 15;
  #pragma unroll
  for (int it = 0; it < 2; ++it) {
    int kl = it*32 + (tid >> 4);
    int gk = kbase + kl;
    int gkc = gk < CAP ? gk : CAP-1;
    const float4* kp = reinterpret_cast<const float4*>(keys + (size_t)gkc*FEAT + dp*8);
    float4 v0 = kp[0], v1 = kp[1];
    float ss = v0.x*v0.x+v0.y*v0.y+v0.z*v0.z+v0.w*v0.w
             + v1.x*v1.x+v1.y*v1.y+v1.z*v1.z+v1.w*v1.w;
    ss += __shfl_xor(ss,1); ss += __shfl_xor(ss,2);
    ss += __shfl_xor(ss,4); ss += __shfl_xor(ss,8);
    if (dp == 0) {
      float scl = 0.0f;
      if (gk < CAP) {
        float age = (float)(g0 - ts[gk]);
        // approx path only: rsqrt rel-err ~1e-7 << MARGIN; exact rescore unaffected
        scl = exp2f(age * -0.00723157f) * __frsqrt_rn(fmaxf(ss, 1e-24f));
      }
      sscale[kl] = scl;
    }
    uint4 pk;
    pk.x = pack2(v0.x, v0.y); pk.y = pack2(v0.z, v0.w);
    pk.z = pack2(v1.x, v1.y); pk.w = pack2(v1.z, v1.w);
    int slab = (kl >> 4)*4 + (dp >> 2);
    int slot = (dp & 3)*16 + (kl & 15);
    lds_kf[slab*66 + slot] = pk;
  }
  __syncthreads();

  float tm0[4], tm1[4];
  #pragma unroll
  for (int t = 0; t < 4; ++t) {
    f32x4 acc0 = {0.f,0.f,0.f,0.f}, acc1 = {0.f,0.f,0.f,0.f};
    #pragma unroll
    for (int s_ = 0; s_ < 4; ++s_) {
      short8 a = __builtin_bit_cast(short8, lds_kf[(t*4 + s_)*66 + lane]);
      acc0 = __builtin_amdgcn_mfma_f32_16x16x32_bf16(a, qf0[s_], acc0, 0,0,0);
      acc1 = __builtin_amdgcn_mfma_f32_16x16x32_bf16(a, qf1[s_], acc1, 0,0,0);
    }
    // C/D: col=lane&15 (query), row=(lane>>4)*4+r (key); pad keys scale=0
    int kbl = t*16 + (lane>>4)*4;
    float4 sc = *reinterpret_cast<float4*>(&sscale[kbl]);
    float m0 = fmaxf(fmaxf(acc0[0]*sc.x, acc0[1]*sc.y),
                     fmaxf(acc0[2]*sc.z, acc0[3]*sc.w));
    float m1 = fmaxf(fmaxf(acc1[0]*sc.x, acc1[1]*sc.y),
                     fmaxf(acc1[2]*sc.z, acc1[3]*sc.w));
    m0 = fmaxf(m0, __shfl_xor(m0,16)); m0 = fmaxf(m0, __shfl_xor(m0,32));
    m1 = fmaxf(m1, __shfl_xor(m1,16)); m1 = fmaxf(m1, __shfl_xor(m1,32));
    tm0[t] = m0; tm1[t] = m1;
  }

  if (lane < 16) {
    int q0 = w*32 + lane, q1 = q0 + 16;
    float4 a0 = {tm0[0],tm0[1],tm0[2],tm0[3]};
    float4 b0 = {tm1[0],tm1[1],tm1[2],tm1[3]};
    *reinterpret_cast<float4*>(&tmax[(size_t)q0*NCHK + blk*4]) = a0;
    *reinterpret_cast<float4*>(&tmax[(size_t)q1*NCHK + blk*4]) = b0;
  }
}

// grid 256 (1/query), block 1024 (16 waves). Value-only m5a scan, margin
// select, exact f32 rescore, exact top-5 + gather. (Unchanged from R13.)
__global__ __launch_bounds__(1024) void select_rescore4(
    const float* __restrict__ tmax, const float* __restrict__ keys,
    const float* __restrict__ query, const int* __restrict__ ts,
    const int* __restrict__ gstep, const float* __restrict__ values,
    float* __restrict__ out) {
  int q = blockIdx.x, tid = threadIdx.x;
  int w = tid >> 6, lane = tid & 63;
  int gstep0 = gstep[0];

  __shared__ float qrow[FEAT];
  if (tid < 16) {
    int d0 = tid * 8;
    const float4* src = reinterpret_cast<const float4*>(query + (size_t)q*FEAT + d0);
    float4 v0 = src[0], v1 = src[1];
    float ss = v0.x*v0.x + v0.y*v0.y + v0.z*v0.z + v0.w*v0.w
             + v1.x*v1.x + v1.y*v1.y + v1.z*v1.z + v1.w*v1.w;
    ss += __shfl_xor(ss,1); ss += __shfl_xor(ss,2);
    ss += __shfl_xor(ss,4); ss += __shfl_xor(ss,8);
    float inv = 1.0f / fmaxf(sqrtf(ss), 1e-12f);
    v0.x*=inv; v0.y*=inv; v0.z*=inv; v0.w*=inv;
    v1.x*=inv; v1.y*=inv; v1.z*=inv; v1.w*=inv;
    float4* dst = reinterpret_cast<float4*>(qrow + d0);
    dst[0] = v0; dst[1] = v1;
  }
  __syncthreads();

  // phase 1: value-only per-thread sorted-5 of chunk maxima
  float cs[SCPT];
  #pragma unroll
  for (int j = 0; j < SCPT; ++j) {
    int c = tid + j*1024;
    cs[j] = (c < NCHKR) ? tmax[(size_t)q*NCHK + c] : -INFINITY;
  }
  float s5[5] = {-INFINITY,-INFINITY,-INFINITY,-INFINITY,-INFINITY};
  #pragma unroll
  for (int j = 0; j < SCPT; ++j) ins_val(cs[j], s5);
  #pragma unroll
  for (int off = 1; off < 64; off <<= 1) {
    float ps[5];
    #pragma unroll
    for (int j=0;j<5;++j) ps[j] = __shfl_xor(s5[j], off);
    #pragma unroll
    for (int j=0;j<5;++j) ins_val(ps[j], s5);
  }
  __shared__ float rS[16][5]; __shared__ int rI[16][5];
  if (lane == 0) {
    #pragma unroll
    for (int j=0;j<5;++j) rS[w][j] = s5[j];
  }
  __syncthreads();
  __shared__ float thSh;
  if (w == 0) {                         // wave-parallel 16-way block merge
    float m5[5] = {-INFINITY,-INFINITY,-INFINITY,-INFINITY,-INFINITY};
    if (lane < 16) {
      #pragma unroll
      for (int j=0;j<5;++j) m5[j] = rS[lane][j];
    }
    #pragma unroll
    for (int off = 1; off < 16; off <<= 1) {
      float ps[5];
      #pragma unroll
      for (int j=0;j<5;++j) ps[j] = __shfl_xor(m5[j], off);
      #pragma unroll
      for (int j=0;j<5;++j) ins_val(ps[j], m5);
    }
    if (lane == 0) thSh = m5[4] - MARGIN;   // m5a - margin
  }
  __syncthreads();
  float th = thSh;

  // phase 2: select chunks within margin (indices recovered here)
  __shared__ int cnt; __shared__ int clist[MAXSEL];
  if (tid == 0) cnt = 0;
  __syncthreads();
  #pragma unroll
  for (int j = 0; j < SCPT; ++j) {
    int c = tid + j*1024;
    if (c < NCHKR && cs[j] >= th) {
      int p = atomicAdd(&cnt, 1);
      if (p < MAXSEL) clist[p] = c;
    }
  }
  __syncthreads();
  int nsel = cnt < MAXSEL ? cnt : MAXSEL;

  // phase 3: exact f32 rescore, 4 threads/key (wave = 16 consecutive keys)
  __shared__ float exs[MAXSEL*16];
  for (int s4 = tid; s4 < nsel*64; s4 += 1024) {
    int slot = s4 >> 2, part = s4 & 3;
    int key = clist[slot >> 4]*16 + (slot & 15);
    float dot = 0.f, ksq = 0.f;
    if (key < CAP) {
      const float4* kp = reinterpret_cast<const float4*>(keys + (size_t)key*FEAT + part*32);
      const float4* qp = reinterpret_cast<float4*>(qrow) + part*8;
      #pragma unroll
      for (int d = 0; d < 8; ++d) {
        float4 kv = kp[d];
        float4 qv = qp[d];
        dot = fmaf(kv.w,qv.w,fmaf(kv.z,qv.z,fmaf(kv.y,qv.y,fmaf(kv.x,qv.x,dot))));
        ksq = fmaf(kv.w,kv.w,fmaf(kv.z,kv.z,fmaf(kv.y,kv.y,fmaf(kv.x,kv.x,ksq))));
      }
    }
    dot += __shfl_xor(dot,1); dot += __shfl_xor(dot,2);
    ksq += __shfl_xor(ksq,1); ksq += __shfl_xor(ksq,2);
    if (part == 0) {
      float sim = -INFINITY;
      if (key < CAP) {
        float age = (float)(gstep0 - ts[key]);
        sim = dot / fmaxf(sqrtf(ksq), 1e-12f) * powf(0.995f, age);
      }
      exs[slot] = sim;
    }
  }
  __syncthreads();

  // phase 4: exact top-5 with idx tie-break (<=768 candidates, 1/thread)
  float fs5[5] = {-INFINITY,-INFINITY,-INFINITY,-INFINITY,-INFINITY};
  int   fi5[5] = {0x7fffffff,0x7fffffff,0x7fffffff,0x7fffffff,0x7fffffff};
  if (tid < nsel*16) {
    fs5[0] = exs[tid];
    fi5[0] = clist[tid >> 4]*16 + (tid & 15);
  }
  #pragma unroll
  for (int off = 1; off < 64; off <<= 1) {
    float ps[5]; int pi[5];
    #pragma unroll
    for (int j=0;j<5;++j){ ps[j]=__shfl_xor(fs5[j],off); pi[j]=__shfl_xor(fi5[j],off); }
    #pragma unroll
    for (int j=0;j<5;++j) ins_cmp(ps[j], pi[j], fs5, fi5);
  }
  if (lane == 0) {
    #pragma unroll
    for (int j=0;j<5;++j){ rS[w][j]=fs5[j]; rI[w][j]=fi5[j]; }
  }
  __syncthreads();
  __shared__ int wix[K];
  if (w == 0) {                         // wave-parallel 16-way final merge
    float fs[5] = {-INFINITY,-INFINITY,-INFINITY,-INFINITY,-INFINITY};
    int   fi[5] = {0x7fffffff,0x7fffffff,0x7fffffff,0x7fffffff,0x7fffffff};
    if (lane < 16) {
      #pragma unroll
      for (int j=0;j<5;++j){ fs[j]=rS[lane][j]; fi[j]=rI[lane][j]; }
    }
    #pragma unroll
    for (int off = 1; off < 16; off <<= 1) {
      float ps[5]; int pi[5];
      #pragma unroll
      for (int j=0;j<5;++j){ ps[j]=__shfl_xor(fs[j],off); pi[j]=__shfl_xor(fi[j],off); }
      #pragma unroll
      for (int j=0;j<5;++j) ins_cmp(ps[j], pi[j], fs, fi);
    }
    if (lane == 0) {
      #pragma unroll
      for (int r = 0; r < K; ++r) {
        out[OUT_SIMS + q*K + r] = fs[r];
        out[OUT_MASK + q*K + r] = (fs[r] >= 0.0f) ? 1.0f : 0.0f;
        out[OUT_IDX  + q*K + r] = (float)fi[r];
        wix[r] = fi[r];
      }
    }
  }
  __syncthreads();
  for (int idx = tid; idx < K*ROWF; idx += 1024) {
    int r = idx / ROWF, e = idx - r*ROWF;
    out[(q*K + r)*ROWF + e] = values[(size_t)wix[r]*ROWF + e];
  }
}

extern "C" void kernel_launch(void* const* d_in, const int* in_sizes, int n_in,
                              void* d_out, int out_size, void* d_ws, size_t ws_size,
                              hipStream_t stream) {
  const float* query  = (const float*)d_in[0];
  const float* keys   = (const float*)d_in[1];
  const float* values = (const float*)d_in[2];
  const int*   ts     = (const int*)d_in[3];
  const int*   gstep  = (const int*)d_in[4];

  float* out  = (float*)d_out;
  float* wsf  = (float*)d_ws;
  uint4* qF   = (uint4*)(wsf + WS_QF);
  float* tmax = wsf + WS_TMAX;

  prep_q<<<16, 256, 0, stream>>>(query, qF);
  gemm_max6<<<NBLKG, 512, 0, stream>>>(keys, ts, gstep, qF, tmax);
  select_rescore4<<<BATCH, 1024, 0, stream>>>(tmax, keys, query, ts, gstep, values, out);
}